// Round 6
// baseline (438.804 us; speedup 1.0000x reference)
//
#include <hip/hip_runtime.h>

typedef __bf16 bf16;
typedef __attribute__((ext_vector_type(2))) bf16 bf16x2;
typedef __attribute__((ext_vector_type(4))) bf16 bf16x4;
typedef __attribute__((ext_vector_type(8))) bf16 bf16x8;
typedef __attribute__((ext_vector_type(4))) float f32x4;
typedef __attribute__((ext_vector_type(16))) float f32x16;
typedef __attribute__((ext_vector_type(4))) int i32x4;
typedef __attribute__((ext_vector_type(2))) int i32x2;

#define MFMA_BF16(a, b, c) __builtin_amdgcn_mfma_f32_16x16x32_bf16((a), (b), (c), 0, 0, 0)
#define MFMA32(a, b, c)    __builtin_amdgcn_mfma_f32_32x32x16_bf16((a), (b), (c), 0, 0, 0)

constexpr int S_LEN = 2048;
constexpr int EMB   = 1024;
constexpr int NHEAD = 16;
constexpr int HDIM  = 64;
constexpr int BATCH = 4;
constexpr int NTOK  = BATCH * S_LEN;   // 8192

// async global->LDS, 16B per lane (m97 pattern: LDS dest must be uniform base + lane*16)
__device__ __forceinline__ void gload_lds16(const bf16* g, bf16* l) {
    __builtin_amdgcn_global_load_lds(
        (const __attribute__((address_space(1))) void*)g,
        (__attribute__((address_space(3))) void*)l, 16, 0, 0);
}

// pack two f32 -> one dword of 2 bf16 (compiler emits v_cvt_pk_bf16_f32; m240: don't hand-asm)
__device__ __forceinline__ int pkbf(float a, float b) {
    bf16x2 t; t[0] = (bf16)a; t[1] = (bf16)b;
    return __builtin_bit_cast(int, t);
}

// half-wave swap primitive (T12). Semantics: r[0] = {a[0:31], b[0:31]}, r[1] = {a[32:63], b[32:63]}.
#if __has_builtin(__builtin_amdgcn_permlane32_swap)
__device__ __forceinline__ i32x2 permswap(int a, int b) {
    return __builtin_amdgcn_permlane32_swap(a, b, false, false);
}
#else
__device__ __forceinline__ i32x2 permswap(int a, int b) {
    int as = __shfl_xor(a, 32);
    int bs = __shfl_xor(b, 32);
    int hx_ = (threadIdx.x >> 5) & 1;
    i32x2 r;
    r[0] = hx_ ? bs : a;
    r[1] = hx_ ? b : as;
    return r;
}
#endif

// ---------------------------------------------------------------------------
// fp32 -> bf16 elementwise convert (n4 = n/4)
// ---------------------------------------------------------------------------
__global__ __launch_bounds__(256)
void cvt_f32_bf16(const float* __restrict__ src, bf16* __restrict__ dst, int n4) {
    int i = blockIdx.x * 256 + threadIdx.x;
    if (i < n4) {
        f32x4 v = ((const f32x4*)src)[i];
        bf16x4 o;
        o[0] = (bf16)v[0]; o[1] = (bf16)v[1]; o[2] = (bf16)v[2]; o[3] = (bf16)v[3];
        ((bf16x4*)dst)[i] = o;
    }
}

// ---------------------------------------------------------------------------
// NT GEMM, m97 structure (unchanged; known-good).
// ---------------------------------------------------------------------------
__global__ __launch_bounds__(256)
void gemm_bt(const bf16* __restrict__ A,
             const bf16* __restrict__ W0, const bf16* __restrict__ W1, const bf16* __restrict__ W2,
             const float* __restrict__ b0, const float* __restrict__ b1, const float* __restrict__ b2,
             void* __restrict__ d0, void* __restrict__ d1, void* __restrict__ d2,
             int fused, float q_scale)
{
    __shared__ bf16 al[128 * 32];
    __shared__ bf16 bl[128 * 32];

    int seg, mode, n0;
    if (fused) { seg = blockIdx.y >> 3; n0 = (blockIdx.y & 7) * 128; mode = (seg == 2) ? 1 : 0; }
    else       { seg = 0;              n0 = blockIdx.y * 128;        mode = 2; }
    const bf16*  W    = seg == 0 ? W0 : (seg == 1 ? W1 : W2);
    const float* bias = seg == 0 ? b0 : (seg == 1 ? b1 : b2);
    void*        C    = seg == 0 ? d0 : (seg == 1 ? d1 : d2);
    const float  osc  = (fused && seg == 0) ? q_scale : 1.0f;

    const int tid  = threadIdx.x;
    const int lane = tid & 63;
    const int w    = tid >> 6;
    const int quad = lane >> 4;
    const int l16  = lane & 15;
    const int wm   = (w >> 1) * 64;
    const int wn   = (w & 1) * 64;
    const int m0   = blockIdx.x * 128;

    f32x4 acc[4][4] = {};

    for (int k0 = 0; k0 < EMB; k0 += 32) {
        #pragma unroll
        for (int c = 0; c < 2; ++c) {
            int idx = c * 256 + tid;            // LDS addr = idx*16B: uniform base + lane*16 per wave
            int row = idx >> 2, kc = idx & 3;
            gload_lds16(A + (size_t)(m0 + row) * EMB + k0 + kc * 8, &al[idx * 8]);
            gload_lds16(W + (size_t)(n0 + row) * EMB + k0 + kc * 8, &bl[idx * 8]);
        }
        __syncthreads();

        bf16x8 afrag[4], bfrag[4];
        #pragma unroll
        for (int t = 0; t < 4; ++t)
            afrag[t] = *(const bf16x8*)&al[(wm + t * 16 + l16) * 32 + quad * 8];
        #pragma unroll
        for (int t = 0; t < 4; ++t)
            bfrag[t] = *(const bf16x8*)&bl[(wn + t * 16 + l16) * 32 + quad * 8];

        #pragma unroll
        for (int mt = 0; mt < 4; ++mt)
            #pragma unroll
            for (int nt = 0; nt < 4; ++nt)
                acc[mt][nt] = MFMA_BF16(afrag[mt], bfrag[nt], acc[mt][nt]);

        __syncthreads();
    }

    // epilogue: C-layout row = quad*4+r, col = l16 (m89-verified)
    #pragma unroll
    for (int mt = 0; mt < 4; ++mt) {
        #pragma unroll
        for (int nt = 0; nt < 4; ++nt) {
            int col = n0 + wn + nt * 16 + l16;
            float bv = bias[col];
            int row0 = m0 + wm + mt * 16 + quad * 4;
            if (mode == 1) {
                int bb = row0 >> 11, s0 = row0 & 2047;
                int hh = col >> 6,   d  = col & 63;
                bf16x4 pk;
                #pragma unroll
                for (int r = 0; r < 4; ++r) pk[r] = (bf16)(acc[mt][nt][r] + bv);
                *(bf16x4*)((bf16*)C + (size_t)((bb * NHEAD + hh) * HDIM + d) * S_LEN + s0) = pk;
            } else if (mode == 0) {
                #pragma unroll
                for (int r = 0; r < 4; ++r)
                    ((bf16*)C)[(size_t)(row0 + r) * EMB + col] = (bf16)((acc[mt][nt][r] + bv) * osc);
            } else {
                #pragma unroll
                for (int r = 0; r < 4; ++r)
                    ((float*)C)[(size_t)(row0 + r) * EMB + col] = acc[mt][nt][r] + bv;
            }
        }
    }
}

// ---------------------------------------------------------------------------
// Flash attention, 32x32 in-reg structure + KV-SPLIT ACROSS WAVES.
//
// Round-5 lesson: XCD swizzle made K/V L2-resident (FETCH 139->24.8MB) and
// dur DIDN'T MOVE (253us). Three different instruction streams = identical
// time => the limiter is the per-wave serial sweep over all 2048 keys
// (64 dependent online-softmax bodies) with only 4 waves/SIMD and zero
// block-supply slack (grid was exactly 4 blocks/CU).
//
// This round: block owns 32 q-rows; its 4 waves each process a DISJOINT
// 512-key slice (16 bodies, 4x shorter serial chain), merging partials
// (m, l, O) via LDS at the end:
//   M = max m_w; L = sum l_w*2^(m_w-M); O = sum O_w*2^(m_w-M); out = O/L.
// Grid 4096 blocks (4x supply slack). Same total MFMA + load-request
// traffic (K/V loads were per-wave before too). LDS 37.5KB -> 4 blk/CU.
// XCD remap kept: all 64 blocks of one (b,h) on one XCD (fb&7==xcd).
// Kept from R4/R5: in-reg P via cvt_pk+permlane32_swap, defer-max THR=8,
// allvalid mask skip, setprio, K ping-pong reg-prefetch, V-hoist.
// ---------------------------------------------------------------------------
__global__ __launch_bounds__(256)
void flash_attn(const bf16* __restrict__ qg, const bf16* __restrict__ kg,
                const bf16* __restrict__ vtg, const int* __restrict__ maskg,
                bf16* __restrict__ ctx)
{
    __shared__ float o_lds[4][32][64];    // per-wave O partials (f32), 32KB
    __shared__ float m_lds[4][32];        // per-wave running max per q-row
    __shared__ float l_lds[4][32];        // per-wave softmax denom per q-row
    __shared__ bf16  bias_lds[2048];      // additive mask bias (bf16), masked path only
    __shared__ float stat_lds[4][32];     // per-wave alpha broadcast (rescale path)

    // ---- XCD-aware remap: fb = xcd + 8*(qi + 64*gg); g = gg*8+xcd ----
    const int fb  = blockIdx.x;
    const int xcd = fb & 7;
    const int rr  = fb >> 3;
    const int qi  = rr & 63;              // 64 q-blocks of 32 rows per (b,h)
    const int gg  = rr >> 6;              // [0,8)
    const int g   = gg * 8 + xcd;         // (b,h) group, [0,64)
    const int h   = g & 15;
    const int b   = g >> 4;
    const int q0  = qi * 32;

    const int tid  = threadIdx.x;
    const int lane = tid & 63;
    const int w    = tid >> 6;            // wave = KV-split index [0,4)
    const int l32  = lane & 31;
    const int hx   = lane >> 5;

    // mask -> bf16 additive bias in LDS (each thread covers 8 keys) + allvalid
    int ok;
    {
        int i = tid * 8;
        i32x4 m0v = *(const i32x4*)(maskg + b * S_LEN + i);
        i32x4 m1v = *(const i32x4*)(maskg + b * S_LEN + i + 4);
        bf16x8 bb;
        ok = 1;
        #pragma unroll
        for (int r = 0; r < 4; ++r) {
            ok &= (m0v[r] != 0) & (m1v[r] != 0);
            bb[r]     = m0v[r] ? (bf16)0.f : (bf16)(-3.0e38f);
            bb[4 + r] = m1v[r] ? (bf16)0.f : (bf16)(-3.0e38f);
        }
        *(bf16x8*)&bias_lds[i] = bb;
    }
    const int allvalid = __syncthreads_and(ok);

    // Q fragments: all 4 waves share the block's 32 q-rows
    bf16x8 qf[4];
    {
        const bf16* qrow = qg + (size_t)(b * S_LEN + q0 + l32) * EMB + h * HDIM + hx * 8;
        qf[0] = *(const bf16x8*)(qrow);
        qf[1] = *(const bf16x8*)(qrow + 16);
        qf[2] = *(const bf16x8*)(qrow + 32);
        qf[3] = *(const bf16x8*)(qrow + 48);
    }

    // wave w covers keys [w*512, (w+1)*512)
    const bf16* kbase = kg + (size_t)(b * S_LEN + w * 512 + l32) * EMB + h * HDIM + hx * 8;
    const bf16* vb0   = vtg + (size_t)((b * NHEAD + h) * HDIM + l32) * S_LEN + w * 512 + hx * 8;
    const bf16* vb1   = vb0 + (size_t)32 * S_LEN;

    float mrow = -1e30f, lpart = 0.f;
    f32x16 o0, o1;
    #pragma unroll
    for (int r = 0; r < 16; ++r) { o0[r] = 0.f; o1[r] = 0.f; }

#define LOADK(DST, KTI) { const bf16* kp_ = kbase + (size_t)(KTI) * 32 * EMB;      \
    DST[0] = *(const bf16x8*)(kp_);      DST[1] = *(const bf16x8*)(kp_ + 16);      \
    DST[2] = *(const bf16x8*)(kp_ + 32); DST[3] = *(const bf16x8*)(kp_ + 48); }

#define BODY(KF, KT) {                                                             \
    const int k0_ = (KT) * 32;                                                     \
    const int kw_ = w * 512 + k0_;   /* absolute key offset for bias */            \
    /* V loads issued FIRST: QK+softmax cover before PV uses them */               \
    bf16x8 vf00 = *(const bf16x8*)(vb0 + k0_);                                     \
    bf16x8 vf10 = *(const bf16x8*)(vb0 + k0_ + 16);                                \
    bf16x8 vf01 = *(const bf16x8*)(vb1 + k0_);                                     \
    bf16x8 vf11 = *(const bf16x8*)(vb1 + k0_ + 16);                                \
    f32x16 s_;                                                                     \
    _Pragma("unroll") for (int r_ = 0; r_ < 16; ++r_) s_[r_] = 0.f;                \
    __builtin_amdgcn_s_setprio(1);                                                 \
    s_ = MFMA32(KF[0], qf[0], s_); s_ = MFMA32(KF[1], qf[1], s_);                  \
    s_ = MFMA32(KF[2], qf[2], s_); s_ = MFMA32(KF[3], qf[3], s_);                  \
    __builtin_amdgcn_s_setprio(0);                                                 \
    if (!allvalid) {                                                               \
        _Pragma("unroll") for (int s4_ = 0; s4_ < 4; ++s4_) {                      \
            bf16x4 b4_ = *(const bf16x4*)&bias_lds[kw_ + s4_ * 8 + hx * 4];        \
            _Pragma("unroll") for (int t_ = 0; t_ < 4; ++t_)                       \
                s_[4 * s4_ + t_] += (float)b4_[t_];                                \
        }                                                                          \
    }                                                                              \
    float rmax_ = s_[0];                                                           \
    _Pragma("unroll") for (int r_ = 1; r_ < 16; ++r_) rmax_ = fmaxf(rmax_, s_[r_]);\
    rmax_ = fmaxf(rmax_, __shfl_xor(rmax_, 32));                                   \
    if (!__all(rmax_ <= mrow + 8.f)) {                                             \
        float mnew_  = fmaxf(mrow, rmax_);                                         \
        float alpha_ = __builtin_amdgcn_exp2f(mrow - mnew_);                       \
        mrow = mnew_; lpart *= alpha_;                                             \
        if (hx == 0) stat_lds[w][l32] = alpha_;                                    \
        _Pragma("unroll") for (int s4_ = 0; s4_ < 4; ++s4_) {                      \
            f32x4 a4_ = *(const f32x4*)&stat_lds[w][s4_ * 8 + hx * 4];             \
            _Pragma("unroll") for (int t_ = 0; t_ < 4; ++t_) {                     \
                o0[4 * s4_ + t_] *= a4_[t_]; o1[4 * s4_ + t_] *= a4_[t_];          \
            }                                                                      \
        }                                                                          \
    }                                                                              \
    bf16x8 pa0, pa1;                                                               \
    {                                                                              \
        float p_[8];                                                               \
        _Pragma("unroll") for (int r_ = 0; r_ < 8; ++r_) {                         \
            p_[r_] = __builtin_amdgcn_exp2f(s_[r_] - mrow); lpart += p_[r_];       \
        }                                                                          \
        i32x2 r0_ = permswap(pkbf(p_[0], p_[1]), pkbf(p_[4], p_[5]));              \
        i32x2 r1_ = permswap(pkbf(p_[2], p_[3]), pkbf(p_[6], p_[7]));              \
        i32x4 fw_; fw_[0] = r0_[0]; fw_[1] = r1_[0]; fw_[2] = r0_[1]; fw_[3] = r1_[1]; \
        pa0 = __builtin_bit_cast(bf16x8, fw_);                                     \
    }                                                                              \
    {                                                                              \
        float p_[8];                                                               \
        _Pragma("unroll") for (int r_ = 0; r_ < 8; ++r_) {                         \
            p_[r_] = __builtin_amdgcn_exp2f(s_[8 + r_] - mrow); lpart += p_[r_];   \
        }                                                                          \
        i32x2 r0_ = permswap(pkbf(p_[0], p_[1]), pkbf(p_[4], p_[5]));              \
        i32x2 r1_ = permswap(pkbf(p_[2], p_[3]), pkbf(p_[6], p_[7]));              \
        i32x4 fw_; fw_[0] = r0_[0]; fw_[1] = r1_[0]; fw_[2] = r0_[1]; fw_[3] = r1_[1]; \
        pa1 = __builtin_bit_cast(bf16x8, fw_);                                     \
    }                                                                              \
    __builtin_amdgcn_s_setprio(1);                                                 \
    o0 = MFMA32(pa0, vf00, o0); o1 = MFMA32(pa0, vf01, o1);                        \
    o0 = MFMA32(pa1, vf10, o0); o1 = MFMA32(pa1, vf11, o1);                        \
    __builtin_amdgcn_s_setprio(0);                                                 \
}

    bf16x8 kfa[4], kfb[4];
    LOADK(kfa, 0)
    for (int kt = 0; kt < 16; kt += 2) {
        LOADK(kfb, kt + 1)
        BODY(kfa, kt)
        int ktn = (kt + 2 < 16) ? kt + 2 : 15;   // last prefetch clamped (redundant, in-bounds)
        LOADK(kfa, ktn)
        BODY(kfb, kt + 1)
    }

#undef BODY
#undef LOADK

    // ---- wave partials -> LDS ----
    float lrow = lpart + __shfl_xor(lpart, 32);   // both halves end with same mrow
    #pragma unroll
    for (int s4 = 0; s4 < 4; ++s4)
        #pragma unroll
        for (int t = 0; t < 4; ++t) {
            int row = s4 * 8 + hx * 4 + t;
            o_lds[w][row][l32]      = o0[4 * s4 + t];
            o_lds[w][row][l32 + 32] = o1[4 * s4 + t];
        }
    if (hx == 0) { m_lds[w][l32] = mrow; l_lds[w][l32] = lrow; }
    __syncthreads();

    // ---- combine 4 KV-split partials, store ctx[b,s,h,d] ----
    {
        const int row = tid >> 3;          // 0..31
        const int d0  = (tid & 7) * 8;     // 0..56
        float m0 = m_lds[0][row], m1 = m_lds[1][row];
        float m2 = m_lds[2][row], m3 = m_lds[3][row];
        float M  = fmaxf(fmaxf(m0, m1), fmaxf(m2, m3));
        float sc[4];
        sc[0] = __builtin_amdgcn_exp2f(m0 - M);
        sc[1] = __builtin_amdgcn_exp2f(m1 - M);
        sc[2] = __builtin_amdgcn_exp2f(m2 - M);
        sc[3] = __builtin_amdgcn_exp2f(m3 - M);
        float L = l_lds[0][row] * sc[0] + l_lds[1][row] * sc[1]
                + l_lds[2][row] * sc[2] + l_lds[3][row] * sc[3];
        float inv = L > 0.f ? 1.f / L : 0.f;
        #pragma unroll
        for (int wv = 0; wv < 4; ++wv) sc[wv] *= inv;

        float acc[8] = {};
        #pragma unroll
        for (int wv = 0; wv < 4; ++wv) {
            f32x4 lo = *(const f32x4*)&o_lds[wv][row][d0];
            f32x4 hi = *(const f32x4*)&o_lds[wv][row][d0 + 4];
            #pragma unroll
            for (int j = 0; j < 4; ++j) {
                acc[j]     += lo[j] * sc[wv];
                acc[4 + j] += hi[j] * sc[wv];
            }
        }
        bf16x8 outv;
        #pragma unroll
        for (int j = 0; j < 8; ++j) outv[j] = (bf16)acc[j];
        *(bf16x8*)(ctx + (size_t)(b * S_LEN + q0 + row) * EMB + h * HDIM + d0) = outv;
    }
}

extern "C" void kernel_launch(void* const* d_in, const int* in_sizes, int n_in,
                              void* d_out, int out_size, void* d_ws, size_t ws_size,
                              hipStream_t stream)
{
    const float* x   = (const float*)d_in[0];
    const int*  mask = (const int*)d_in[1];
    const float* Wq  = (const float*)d_in[2];
    const float* bq  = (const float*)d_in[3];
    const float* Wk  = (const float*)d_in[4];
    const float* bk  = (const float*)d_in[5];
    const float* Wv  = (const float*)d_in[6];
    const float* bv  = (const float*)d_in[7];
    const float* Wo  = (const float*)d_in[8];
    const float* bo  = (const float*)d_in[9];
    (void)in_sizes; (void)n_in; (void)out_size; (void)ws_size;

    const size_t me = (size_t)NTOK * EMB;    // 8.4M
    const size_t we = (size_t)EMB * EMB;     // 1M
    bf16* xb  = (bf16*)d_ws;
    bf16* qb  = xb  + me;
    bf16* kb  = qb  + me;
    bf16* vt  = kb  + me;     // V transposed [b,h,d,s]
    bf16* wqb = vt  + me;
    bf16* wkb = wqb + we;
    bf16* wvb = wkb + we;
    bf16* wob = wvb + we;
    bf16* cx  = xb;           // alias: xb consumed by qkv gemm before flash writes cx

    cvt_f32_bf16<<<(int)(me / 4 / 256), 256, 0, stream>>>(x,  xb,  (int)(me / 4));
    cvt_f32_bf16<<<(int)(we / 4 / 256), 256, 0, stream>>>(Wq, wqb, (int)(we / 4));
    cvt_f32_bf16<<<(int)(we / 4 / 256), 256, 0, stream>>>(Wk, wkb, (int)(we / 4));
    cvt_f32_bf16<<<(int)(we / 4 / 256), 256, 0, stream>>>(Wv, wvb, (int)(we / 4));
    cvt_f32_bf16<<<(int)(we / 4 / 256), 256, 0, stream>>>(Wo, wob, (int)(we / 4));

    // q_scale = 1/sqrt(HDIM) * log2(e), folded into Q so flash softmax is scale-free
    gemm_bt<<<dim3(NTOK / 128, 24), 256, 0, stream>>>(
        xb, wqb, wkb, wvb, bq, bk, bv, qb, kb, vt, 1, 0.18033688011112042f);

    flash_attn<<<dim3(4096), 256, 0, stream>>>(qb, kb, vt, mask, cx);

    gemm_bt<<<dim3(NTOK / 128, EMB / 128), 256, 0, stream>>>(
        cx, wob, wob, wob, bo, bo, bo, d_out, d_out, d_out, 0, 1.0f);
}

// Round 7
// 282.687 us; speedup vs baseline: 1.5523x; 1.5523x over previous
//
#include <hip/hip_runtime.h>

typedef __bf16 bf16;
typedef __attribute__((ext_vector_type(2))) bf16 bf16x2;
typedef __attribute__((ext_vector_type(4))) bf16 bf16x4;
typedef __attribute__((ext_vector_type(8))) bf16 bf16x8;
typedef __attribute__((ext_vector_type(4))) float f32x4;
typedef __attribute__((ext_vector_type(16))) float f32x16;
typedef __attribute__((ext_vector_type(4))) int i32x4;
typedef __attribute__((ext_vector_type(2))) int i32x2;

#define MFMA_BF16(a, b, c) __builtin_amdgcn_mfma_f32_16x16x32_bf16((a), (b), (c), 0, 0, 0)
#define MFMA32(a, b, c)    __builtin_amdgcn_mfma_f32_32x32x16_bf16((a), (b), (c), 0, 0, 0)

constexpr int S_LEN = 2048;
constexpr int EMB   = 1024;
constexpr int NHEAD = 16;
constexpr int HDIM  = 64;
constexpr int BATCH = 4;
constexpr int NTOK  = BATCH * S_LEN;   // 8192

// async global->LDS, 16B per lane (m97 pattern: LDS dest must be uniform base + lane*16)
__device__ __forceinline__ void gload_lds16(const bf16* g, bf16* l) {
    __builtin_amdgcn_global_load_lds(
        (const __attribute__((address_space(1))) void*)g,
        (__attribute__((address_space(3))) void*)l, 16, 0, 0);
}

// pack two f32 -> one dword of 2 bf16 (compiler emits v_cvt_pk_bf16_f32; m240: don't hand-asm)
__device__ __forceinline__ int pkbf(float a, float b) {
    bf16x2 t; t[0] = (bf16)a; t[1] = (bf16)b;
    return __builtin_bit_cast(int, t);
}

// half-wave swap primitive (T12). Semantics: r[0] = {a[0:31], b[0:31]}, r[1] = {a[32:63], b[32:63]}.
#if __has_builtin(__builtin_amdgcn_permlane32_swap)
__device__ __forceinline__ i32x2 permswap(int a, int b) {
    return __builtin_amdgcn_permlane32_swap(a, b, false, false);
}
#else
__device__ __forceinline__ i32x2 permswap(int a, int b) {
    int as = __shfl_xor(a, 32);
    int bs = __shfl_xor(b, 32);
    int hx_ = (threadIdx.x >> 5) & 1;
    i32x2 r;
    r[0] = hx_ ? bs : a;
    r[1] = hx_ ? b : as;
    return r;
}
#endif

// ---------------------------------------------------------------------------
// fp32 -> bf16 elementwise convert (n4 = n/4)
// ---------------------------------------------------------------------------
__global__ __launch_bounds__(256)
void cvt_f32_bf16(const float* __restrict__ src, bf16* __restrict__ dst, int n4) {
    int i = blockIdx.x * 256 + threadIdx.x;
    if (i < n4) {
        f32x4 v = ((const f32x4*)src)[i];
        bf16x4 o;
        o[0] = (bf16)v[0]; o[1] = (bf16)v[1]; o[2] = (bf16)v[2]; o[3] = (bf16)v[3];
        ((bf16x4*)dst)[i] = o;
    }
}

// ---------------------------------------------------------------------------
// NT GEMM, m97 structure (unchanged; known-good).
// ---------------------------------------------------------------------------
__global__ __launch_bounds__(256)
void gemm_bt(const bf16* __restrict__ A,
             const bf16* __restrict__ W0, const bf16* __restrict__ W1, const bf16* __restrict__ W2,
             const float* __restrict__ b0, const float* __restrict__ b1, const float* __restrict__ b2,
             void* __restrict__ d0, void* __restrict__ d1, void* __restrict__ d2,
             int fused, float q_scale)
{
    __shared__ bf16 al[128 * 32];
    __shared__ bf16 bl[128 * 32];

    int seg, mode, n0;
    if (fused) { seg = blockIdx.y >> 3; n0 = (blockIdx.y & 7) * 128; mode = (seg == 2) ? 1 : 0; }
    else       { seg = 0;              n0 = blockIdx.y * 128;        mode = 2; }
    const bf16*  W    = seg == 0 ? W0 : (seg == 1 ? W1 : W2);
    const float* bias = seg == 0 ? b0 : (seg == 1 ? b1 : b2);
    void*        C    = seg == 0 ? d0 : (seg == 1 ? d1 : d2);
    const float  osc  = (fused && seg == 0) ? q_scale : 1.0f;

    const int tid  = threadIdx.x;
    const int lane = tid & 63;
    const int w    = tid >> 6;
    const int quad = lane >> 4;
    const int l16  = lane & 15;
    const int wm   = (w >> 1) * 64;
    const int wn   = (w & 1) * 64;
    const int m0   = blockIdx.x * 128;

    f32x4 acc[4][4] = {};

    for (int k0 = 0; k0 < EMB; k0 += 32) {
        #pragma unroll
        for (int c = 0; c < 2; ++c) {
            int idx = c * 256 + tid;            // LDS addr = idx*16B: uniform base + lane*16 per wave
            int row = idx >> 2, kc = idx & 3;
            gload_lds16(A + (size_t)(m0 + row) * EMB + k0 + kc * 8, &al[idx * 8]);
            gload_lds16(W + (size_t)(n0 + row) * EMB + k0 + kc * 8, &bl[idx * 8]);
        }
        __syncthreads();

        bf16x8 afrag[4], bfrag[4];
        #pragma unroll
        for (int t = 0; t < 4; ++t)
            afrag[t] = *(const bf16x8*)&al[(wm + t * 16 + l16) * 32 + quad * 8];
        #pragma unroll
        for (int t = 0; t < 4; ++t)
            bfrag[t] = *(const bf16x8*)&bl[(wn + t * 16 + l16) * 32 + quad * 8];

        #pragma unroll
        for (int mt = 0; mt < 4; ++mt)
            #pragma unroll
            for (int nt = 0; nt < 4; ++nt)
                acc[mt][nt] = MFMA_BF16(afrag[mt], bfrag[nt], acc[mt][nt]);

        __syncthreads();
    }

    // epilogue: C-layout row = quad*4+r, col = l16 (m89-verified)
    #pragma unroll
    for (int mt = 0; mt < 4; ++mt) {
        #pragma unroll
        for (int nt = 0; nt < 4; ++nt) {
            int col = n0 + wn + nt * 16 + l16;
            float bv = bias[col];
            int row0 = m0 + wm + mt * 16 + quad * 4;
            if (mode == 1) {
                int bb = row0 >> 11, s0 = row0 & 2047;
                int hh = col >> 6,   d  = col & 63;
                bf16x4 pk;
                #pragma unroll
                for (int r = 0; r < 4; ++r) pk[r] = (bf16)(acc[mt][nt][r] + bv);
                *(bf16x4*)((bf16*)C + (size_t)((bb * NHEAD + hh) * HDIM + d) * S_LEN + s0) = pk;
            } else if (mode == 0) {
                #pragma unroll
                for (int r = 0; r < 4; ++r)
                    ((bf16*)C)[(size_t)(row0 + r) * EMB + col] = (bf16)((acc[mt][nt][r] + bv) * osc);
            } else {
                #pragma unroll
                for (int r = 0; r < 4; ++r)
                    ((float*)C)[(size_t)(row0 + r) * EMB + col] = acc[mt][nt][r] + bv;
            }
        }
    }
}

// ---------------------------------------------------------------------------
// Flash attention, m214-style: 8 waves x 32 q-rows = 256 q-rows/block,
// KVBLK=64 double-buffered in LDS via global_load_lds, one barrier per tile.
//
// Round-6 lesson: chain-shortening (R6), locality (R5), structure (R4) were
// ALL null at ~253-266us. FETCH_SIZE only excludes HBM — it does not prove
// L2 hits. Per-XCD working set (4MB K/V + streaming Q + ctx) exceeds the
// 4MB L2, so direct-to-register K/V loads are served by L3 at ~600-900cy;
// per-body prefetch cover (~300cy) can't hide it. The shared invariant of
// all six kernels was per-wave direct global K/V loads.
//
// Fix (T3-minimum + rule #21): K/V tiles staged cooperatively into LDS
// (8KB each), double-buffered; STAGE(next) issued BEFORE compute so the
// global latency hides under a full tile of 8-wave compute + the barrier.
// Waves read operands from LDS (b128, XOR-swizzled: linear gload_lds dest +
// inverse-swizzled GLOBAL source + swizzled ds_read; slot ^= row&7).
// 8 waves share one staged copy (8x less K/V read volume). Per-wave math
// (swapped-QK sacc layout, defer-max THR=8, cvt_pk+permswap P-build, PV,
// epilogue) carried over verbatim from the R4-R6 verified kernels.
// Grid 512 blocks (XCD-remapped), 512 threads. LDS ~37KB.
// ---------------------------------------------------------------------------
__global__ __launch_bounds__(512)
void flash_attn(const bf16* __restrict__ qg, const bf16* __restrict__ kg,
                const bf16* __restrict__ vtg, const int* __restrict__ maskg,
                bf16* __restrict__ ctx)
{
    __shared__ bf16  klds[2][64 * 64];    // [key][d-elem], 128B rows, slot-swizzled, 8KB each
    __shared__ bf16  vlds[2][64 * 64];    // [d][key-elem], 128B rows, slot-swizzled, 8KB each
    __shared__ bf16  bias_lds[2048];      // additive mask bias (bf16), masked path only
    __shared__ float stat_lds[8][32];     // per-wave alpha / inv-l broadcast

    // ---- XCD remap: fb = xcd + 8*(qi + 8*gg); g = gg*8+xcd; bijective 512 ----
    const int fb  = blockIdx.x;
    const int xcd = fb & 7;
    const int rr  = fb >> 3;
    const int qi  = rr & 7;               // 8 q-blocks of 256 rows per (b,h)
    const int gg  = rr >> 3;              // [0,8)
    const int g   = gg * 8 + xcd;         // (b,h) group, [0,64)
    const int h   = g & 15;
    const int b   = g >> 4;
    const int q0  = qi * 256;

    const int tid  = threadIdx.x;         // 0..511
    const int lane = tid & 63;
    const int w    = tid >> 6;            // wave 0..7
    const int l32  = lane & 31;
    const int hx   = lane >> 5;

    // staging coords: thread t covers LDS row t>>3, 16B slot t&7 (linear dest)
    const int srow  = tid >> 3;
    const int sslot = (tid & 7) ^ (srow & 7);   // inverse-swizzled global slot

    // mask -> bf16 additive bias in LDS (each thread covers 4 keys) + allvalid
    int ok;
    {
        int i = tid * 4;
        i32x4 mv = *(const i32x4*)(maskg + b * S_LEN + i);
        bf16x4 bb;
        ok = 1;
        #pragma unroll
        for (int r = 0; r < 4; ++r) {
            ok &= (mv[r] != 0);
            bb[r] = mv[r] ? (bf16)0.f : (bf16)(-3.0e38f);
        }
        *(bf16x4*)&bias_lds[i] = bb;
    }
    const int allvalid = __syncthreads_and(ok);

    // Q fragments (B-operand: col=query=l32, k = c*16 + hx*8 + j), resident
    bf16x8 qf[4];
    {
        const bf16* qrow = qg + (size_t)(b * S_LEN + q0 + w * 32 + l32) * EMB + h * HDIM + hx * 8;
        qf[0] = *(const bf16x8*)(qrow);
        qf[1] = *(const bf16x8*)(qrow + 16);
        qf[2] = *(const bf16x8*)(qrow + 32);
        qf[3] = *(const bf16x8*)(qrow + 48);
    }

    const bf16* kgb = kg  + (size_t)b * S_LEN * EMB + h * HDIM;              // + key*EMB
    const bf16* vgb = vtg + (size_t)((b * NHEAD + h) * HDIM) * S_LEN;        // + d*S_LEN + key

    float mrow = -1e30f, lpart = 0.f;
    f32x16 o0, o1;
    #pragma unroll
    for (int r = 0; r < 16; ++r) { o0[r] = 0.f; o1[r] = 0.f; }

    // stage K/V tile KT into buffer BUF (512 thr x 16B = 8KB each; linear LDS dest,
    // inverse-swizzled global source per rule #21)
#define STAGE(BUF, KT) {                                                            \
    gload_lds16(kgb + (size_t)((KT) * 64 + srow) * EMB + sslot * 8,                 \
                &klds[BUF][tid * 8]);                                               \
    gload_lds16(vgb + (size_t)srow * S_LEN + (KT) * 64 + sslot * 8,                 \
                &vlds[BUF][tid * 8]);                                               \
}

    // swizzled LDS reads: row, slotbase -> 16B at row*128 + ((slotbase^(row&7))<<4)
#define LDSK(CUR, ROW, SB) (*(const bf16x8*)((const char*)&klds[CUR][0] + ((ROW) << 7) + ((((SB) ^ ((ROW) & 7))) << 4)))
#define LDSV(CUR, ROW, SB) (*(const bf16x8*)((const char*)&vlds[CUR][0] + ((ROW) << 7) + ((((SB) ^ ((ROW) & 7))) << 4)))

    // one 32-key subtile: QK from klds, online softmax (verbatim R6 math), PV from vlds
#define SUBTILE(CUR, KT, KK) {                                                      \
    f32x16 s_;                                                                      \
    _Pragma("unroll") for (int r_ = 0; r_ < 16; ++r_) s_[r_] = 0.f;                 \
    const int krow_ = (KK) * 32 + l32;                                              \
    __builtin_amdgcn_s_setprio(1);                                                  \
    s_ = MFMA32(LDSK(CUR, krow_, 0 * 2 + hx), qf[0], s_);                           \
    s_ = MFMA32(LDSK(CUR, krow_, 1 * 2 + hx), qf[1], s_);                           \
    s_ = MFMA32(LDSK(CUR, krow_, 2 * 2 + hx), qf[2], s_);                           \
    s_ = MFMA32(LDSK(CUR, krow_, 3 * 2 + hx), qf[3], s_);                           \
    __builtin_amdgcn_s_setprio(0);                                                  \
    if (!allvalid) {                                                                \
        _Pragma("unroll") for (int s4_ = 0; s4_ < 4; ++s4_) {                       \
            bf16x4 b4_ = *(const bf16x4*)&bias_lds[(KT) * 64 + (KK) * 32 + s4_ * 8 + hx * 4]; \
            _Pragma("unroll") for (int t_ = 0; t_ < 4; ++t_)                        \
                s_[4 * s4_ + t_] += (float)b4_[t_];                                 \
        }                                                                           \
    }                                                                               \
    float rmax_ = s_[0];                                                            \
    _Pragma("unroll") for (int r_ = 1; r_ < 16; ++r_) rmax_ = fmaxf(rmax_, s_[r_]); \
    rmax_ = fmaxf(rmax_, __shfl_xor(rmax_, 32));                                    \
    if (!__all(rmax_ <= mrow + 8.f)) {                                              \
        float mnew_  = fmaxf(mrow, rmax_);                                          \
        float alpha_ = __builtin_amdgcn_exp2f(mrow - mnew_);                        \
        mrow = mnew_; lpart *= alpha_;                                              \
        if (hx == 0) stat_lds[w][l32] = alpha_;                                     \
        _Pragma("unroll") for (int s4_ = 0; s4_ < 4; ++s4_) {                       \
            f32x4 a4_ = *(const f32x4*)&stat_lds[w][s4_ * 8 + hx * 4];              \
            _Pragma("unroll") for (int t_ = 0; t_ < 4; ++t_) {                      \
                o0[4 * s4_ + t_] *= a4_[t_]; o1[4 * s4_ + t_] *= a4_[t_];           \
            }                                                                       \
        }                                                                           \
    }                                                                               \
    bf16x8 pa0, pa1;                                                                \
    {                                                                               \
        float p_[8];                                                                \
        _Pragma("unroll") for (int r_ = 0; r_ < 8; ++r_) {                          \
            p_[r_] = __builtin_amdgcn_exp2f(s_[r_] - mrow); lpart += p_[r_];        \
        }                                                                           \
        i32x2 r0_ = permswap(pkbf(p_[0], p_[1]), pkbf(p_[4], p_[5]));               \
        i32x2 r1_ = permswap(pkbf(p_[2], p_[3]), pkbf(p_[6], p_[7]));               \
        i32x4 fw_; fw_[0] = r0_[0]; fw_[1] = r1_[0]; fw_[2] = r0_[1]; fw_[3] = r1_[1]; \
        pa0 = __builtin_bit_cast(bf16x8, fw_);                                      \
    }                                                                               \
    {                                                                               \
        float p_[8];                                                                \
        _Pragma("unroll") for (int r_ = 0; r_ < 8; ++r_) {                          \
            p_[r_] = __builtin_amdgcn_exp2f(s_[8 + r_] - mrow); lpart += p_[r_];    \
        }                                                                           \
        i32x2 r0_ = permswap(pkbf(p_[0], p_[1]), pkbf(p_[4], p_[5]));               \
        i32x2 r1_ = permswap(pkbf(p_[2], p_[3]), pkbf(p_[6], p_[7]));               \
        i32x4 fw_; fw_[0] = r0_[0]; fw_[1] = r1_[0]; fw_[2] = r0_[1]; fw_[3] = r1_[1]; \
        pa1 = __builtin_bit_cast(bf16x8, fw_);                                      \
    }                                                                               \
    __builtin_amdgcn_s_setprio(1);                                                  \
    o0 = MFMA32(pa0, LDSV(CUR, 0 * 32 + l32, (KK) * 4 + 0 * 2 + hx), o0);           \
    o1 = MFMA32(pa0, LDSV(CUR, 1 * 32 + l32, (KK) * 4 + 0 * 2 + hx), o1);           \
    o0 = MFMA32(pa1, LDSV(CUR, 0 * 32 + l32, (KK) * 4 + 1 * 2 + hx), o0);           \
    o1 = MFMA32(pa1, LDSV(CUR, 1 * 32 + l32, (KK) * 4 + 1 * 2 + hx), o1);           \
    __builtin_amdgcn_s_setprio(0);                                                  \
}

    // prologue: stage tile 0, drain, barrier
    STAGE(0, 0)
    __syncthreads();   // compiler emits vmcnt(0)+lgkmcnt(0) drain before s_barrier

    for (int kt = 0; kt < 32; ++kt) {
        const int cur = kt & 1;
        if (kt + 1 < 32) STAGE(cur ^ 1, kt + 1)   // issue next-tile loads FIRST
        SUBTILE(cur, kt, 0)
        SUBTILE(cur, kt, 1)
        __syncthreads();   // drains this iter's stage loads + all waves done reading buf[cur]
    }

#undef SUBTILE
#undef LDSK
#undef LDSV
#undef STAGE

    // ---- epilogue: cross-half l reduce, 1/l broadcast, store ctx[b,s,h,d] ----
    float lrow = lpart + __shfl_xor(lpart, 32);
    float inv  = lrow > 0.f ? 1.f / lrow : 0.f;
    if (hx == 0) stat_lds[w][l32] = inv;
    #pragma unroll
    for (int s4 = 0; s4 < 4; ++s4) {
        f32x4 i4 = *(const f32x4*)&stat_lds[w][s4 * 8 + hx * 4];
        #pragma unroll
        for (int t = 0; t < 4; ++t) {
            size_t row = (size_t)(b * S_LEN + q0 + w * 32 + s4 * 8 + hx * 4 + t);
            bf16* cp = ctx + row * EMB + h * HDIM + l32;
            cp[0]  = (bf16)(o0[4 * s4 + t] * i4[t]);
            cp[32] = (bf16)(o1[4 * s4 + t] * i4[t]);
        }
    }
}

extern "C" void kernel_launch(void* const* d_in, const int* in_sizes, int n_in,
                              void* d_out, int out_size, void* d_ws, size_t ws_size,
                              hipStream_t stream)
{
    const float* x   = (const float*)d_in[0];
    const int*  mask = (const int*)d_in[1];
    const float* Wq  = (const float*)d_in[2];
    const float* bq  = (const float*)d_in[3];
    const float* Wk  = (const float*)d_in[4];
    const float* bk  = (const float*)d_in[5];
    const float* Wv  = (const float*)d_in[6];
    const float* bv  = (const float*)d_in[7];
    const float* Wo  = (const float*)d_in[8];
    const float* bo  = (const float*)d_in[9];
    (void)in_sizes; (void)n_in; (void)out_size; (void)ws_size;

    const size_t me = (size_t)NTOK * EMB;    // 8.4M
    const size_t we = (size_t)EMB * EMB;     // 1M
    bf16* xb  = (bf16*)d_ws;
    bf16* qb  = xb  + me;
    bf16* kb  = qb  + me;
    bf16* vt  = kb  + me;     // V transposed [b,h,d,s]
    bf16* wqb = vt  + me;
    bf16* wkb = wqb + we;
    bf16* wvb = wkb + we;
    bf16* wob = wvb + we;
    bf16* cx  = xb;           // alias: xb consumed by qkv gemm before flash writes cx

    cvt_f32_bf16<<<(int)(me / 4 / 256), 256, 0, stream>>>(x,  xb,  (int)(me / 4));
    cvt_f32_bf16<<<(int)(we / 4 / 256), 256, 0, stream>>>(Wq, wqb, (int)(we / 4));
    cvt_f32_bf16<<<(int)(we / 4 / 256), 256, 0, stream>>>(Wk, wkb, (int)(we / 4));
    cvt_f32_bf16<<<(int)(we / 4 / 256), 256, 0, stream>>>(Wv, wvb, (int)(we / 4));
    cvt_f32_bf16<<<(int)(we / 4 / 256), 256, 0, stream>>>(Wo, wob, (int)(we / 4));

    // q_scale = 1/sqrt(HDIM) * log2(e), folded into Q so flash softmax is scale-free
    gemm_bt<<<dim3(NTOK / 128, 24), 256, 0, stream>>>(
        xb, wqb, wkb, wvb, bq, bk, bv, qb, kb, vt, 1, 0.18033688011112042f);

    flash_attn<<<dim3(512), 512, 0, stream>>>(qb, kb, vt, mask, cx);

    gemm_bt<<<dim3(NTOK / 128, EMB / 128), 256, 0, stream>>>(
        cx, wob, wob, wob, bo, bo, bo, d_out, d_out, d_out, 0, 1.0f);
}